// Round 12
// baseline (123.857 us; speedup 1.0000x reference)
//
#include <hip/hip_runtime.h>

#define N_NODES 50000
#define E_EDGES 250000
#define IN_F 9
#define OUT_F 84
#define GROUPS 21            // OUT_F / 4
#define BN_EPS 1e-5f

#define NB_TILE 48           // nodes per block-tile
#define NTILES ((N_NODES + NB_TILE - 1) / NB_TILE)   // 1042
#define NCOPIES 32           // sharded Gram accumulators
#define CAP 32               // slots per destination (P[deg>32] ~ 1e-11, Poisson(5))
#define RECF 12              // floats per record: x[9], ea, pad, pad (48 B)

#define VDIM 27              // v = (x[9], S0[9], S1[9])
#define NPAIR 378            // VDIM*(VDIM+1)/2 upper-triangle entries of M
#define NM 405               // NPAIR + VDIM (Sigma v)
#define SLEN 408             // padded stride per stat copy

// ws layout (4-byte units):
//   [0, 50000)            : cnt[N] per-dst degree counters (int, memset 0)
//   [50048, 63104)        : statc — 32 copies x 408 (M[378], Sv[27]) (float)
//   [63232, +N*CAP*12)    : slot records {x[9], ea, pad, pad} (76.8 MB)
//   [19263232, +N*18)     : S[N*18] per node S0[9], S1[9] (float)
#define CNT_OFF   0
#define STATC_OFF 50048
#define SLOT_OFF  63232      // *4 B = 252928, %16 == 0
#define S_OFF     19263232

// ---------------------------------------------------------------------------
// K1: bucket edges by destination, embedding the source row:
//   slot[dst][pos] = { x[src][0..8], ea, 0, 0 }   (3 x float4 stores)
// The random x-row read happens HERE (producer, latency-tolerant, contiguous
// 36B per edge) so the consumer never gathers. One atomicAdd per edge.
// Block 0 also zeroes the 32 Gram copies.
// ---------------------------------------------------------------------------
__global__ void fill_slots_kernel(const float* __restrict__ x,
                                  const int* __restrict__ ei,
                                  const float* __restrict__ ea,
                                  int* __restrict__ cnt,
                                  float* __restrict__ slot,
                                  float* __restrict__ statc) {
    if (blockIdx.x == 0) {
        for (int t = threadIdx.x; t < NCOPIES * SLEN; t += blockDim.x)
            statc[t] = 0.0f;
    }
    int e = blockIdx.x * blockDim.x + threadIdx.x;
    if (e < E_EDGES) {
        int   src = ei[e];
        int   dst = ei[E_EDGES + e];
        float a   = ea[e];
        int   pos = atomicAdd(&cnt[dst], 1);
        if (pos < CAP) {
            const float* xr = &x[src * IN_F];     // 36B contiguous
            float x0 = xr[0], x1 = xr[1], x2 = xr[2], x3 = xr[3];
            float x4 = xr[4], x5 = xr[5], x6 = xr[6], x7 = xr[7];
            float x8 = xr[8];
            float4* r = (float4*)&slot[((long)dst * CAP + pos) * RECF];
            r[0] = make_float4(x0, x1, x2, x3);
            r[1] = make_float4(x4, x5, x6, x7);
            r[2] = make_float4(x8, a, 0.f, 0.f);
        }
    }
}

// ---------------------------------------------------------------------------
// K2: gather + Gram, 48-node tiles — chase-free AND gather-free.
//  phase 1: 432 (n,i) items stream their node's records sequentially
//           (stride-48 x_i load + broadcast ea load, all independent)
//  phase 2: Gram M_ij = sum_n V_i V_j (378) + Sv (27), sharded atomic fold
// ---------------------------------------------------------------------------
__global__ void gather_gram_kernel(const float* __restrict__ x,
                                   const int*   __restrict__ cnt,
                                   const float* __restrict__ slot,
                                   float* __restrict__ S,
                                   float* __restrict__ statc) {
    __shared__ float V[VDIM * (NB_TILE + 1)];        // [27][49]
    __shared__ int cnt_s[NB_TILE];
    __shared__ unsigned char pI[NPAIR], pJ[NPAIR];

    const int tid = threadIdx.x;
    const int nbase = blockIdx.x * NB_TILE;

    // pair table (upper triangle, row-major): t -> (i, j)
    for (int t = tid; t < NPAIR; t += blockDim.x) {
        int tt = t, i = 0;
        while (tt >= VDIM - i) { tt -= VDIM - i; ++i; }
        pI[t] = (unsigned char)i;
        pJ[t] = (unsigned char)(i + tt);
    }
    if (tid < NB_TILE) {
        int n = nbase + tid;
        int c = (n < N_NODES) ? cnt[n] : 0;
        cnt_s[tid] = (c > CAP) ? CAP : c;
    }
    __syncthreads();

    // phase 1: stream records — 432 items over 256 threads
    for (int it = tid; it < NB_TILE * IN_F; it += blockDim.x) {
        int nl = it / IN_F, i = it - nl * IN_F;
        int n = nbase + nl;
        float xv = 0.f, s0 = 0.f, s1 = 0.f;
        if (n < N_NODES) {
            xv = x[n * IN_F + i];
            int c = cnt_s[nl];
            const float* row = &slot[(long)n * CAP * RECF];
            int k = 0;
            for (; k + 2 <= c; k += 2) {            // 4 independent loads/iter
                float a0 = row[k * RECF + i];
                float e0 = row[k * RECF + 9];
                float a1 = row[(k + 1) * RECF + i];
                float e1 = row[(k + 1) * RECF + 9];
                s0 += a0 + a1;
                s1 += e0 * a0 + e1 * a1;
            }
            if (k < c) {
                float a0 = row[k * RECF + i];
                float e0 = row[k * RECF + 9];
                s0 += a0;
                s1 += e0 * a0;
            }
            S[n * 18 + i]     = s0;
            S[n * 18 + 9 + i] = s1;
        }
        V[i * (NB_TILE + 1) + nl]        = xv;
        V[(9 + i) * (NB_TILE + 1) + nl]  = s0;
        V[(18 + i) * (NB_TILE + 1) + nl] = s1;
    }
    __syncthreads();

    // phase 2: Gram entries, sharded fold
    float* sc = statc + (blockIdx.x & (NCOPIES - 1)) * SLEN;
    for (int t = tid; t < NM; t += blockDim.x) {
        float acc = 0.f;
        if (t < NPAIR) {
            const float* vi = &V[pI[t] * (NB_TILE + 1)];
            const float* vj = &V[pJ[t] * (NB_TILE + 1)];
#pragma unroll
            for (int n = 0; n < NB_TILE; ++n) acc += vi[n] * vj[n];
        } else {
            const float* vi = &V[(t - NPAIR) * (NB_TILE + 1)];
#pragma unroll
            for (int n = 0; n < NB_TILE; ++n) acc += vi[n];
        }
        atomicAdd(&sc[t], acc);
    }
}

// ---------------------------------------------------------------------------
// K3: final — reduce Gram copies, derive BN scale/shift analytically (all
// from LDS), matvec + normalized write in one pass. 1008 = 252*4 items.
//   sumsq_o = c^T M c + 2 b (Sv.c) + N b^2,  sum_o = Sv.c + N b
// ---------------------------------------------------------------------------
__global__ void final_kernel(const float* __restrict__ x,
                             const float* __restrict__ S,
                             const float* __restrict__ nw,
                             const float* __restrict__ nb,
                             const float* __restrict__ root,
                             const float* __restrict__ bias,
                             const float* __restrict__ gamma,
                             const float* __restrict__ beta,
                             const float* __restrict__ statc,
                             float* __restrict__ out) {
    __shared__ __align__(16) float4 Ws[IN_F * GROUPS];
    __shared__ __align__(16) float4 Bs[IN_F * GROUPS];
    __shared__ __align__(16) float4 Rs[IN_F * GROUPS];
    __shared__ __align__(16) float4 bs4[GROUPS];
    __shared__ float M[NM];
    __shared__ __align__(16) float scale[OUT_F];
    __shared__ __align__(16) float shift[OUT_F];
    __shared__ float Xt[NB_TILE * IN_F];
    __shared__ float St[NB_TILE * 18];

    const int tid = threadIdx.x;
    const int nbase = blockIdx.x * NB_TILE;

    // stage weights
    for (int t = tid; t < IN_F * GROUPS; t += blockDim.x) {
        Ws[t] = ((const float4*)nw)[t];
        Bs[t] = ((const float4*)nb)[t];
        Rs[t] = ((const float4*)root)[t];
    }
    if (tid < GROUPS) bs4[tid] = ((const float4*)bias)[tid];

    // stage tile x and S (432 items, coalesced)
    for (int it = tid; it < NB_TILE * IN_F; it += blockDim.x) {
        int nl = it / IN_F, i = it - nl * IN_F;
        int n = nbase + nl;
        float xv = 0.f, s0 = 0.f, s1 = 0.f;
        if (n < N_NODES) {
            xv = x[n * IN_F + i];
            s0 = S[n * 18 + i];
            s1 = S[n * 18 + 9 + i];
        }
        Xt[nl * IN_F + i]   = xv;
        St[nl * 18 + i]     = s0;
        St[nl * 18 + 9 + i] = s1;
    }

    // reduce the 32 Gram copies
    for (int t = tid; t < NM; t += blockDim.x) {
        float a = 0.f;
#pragma unroll
        for (int c = 0; c < NCOPIES; ++c) a += statc[c * SLEN + t];
        M[t] = a;
    }
    __syncthreads();

    // scale/shift per channel — operands in LDS
    if (tid < OUT_F) {
        const int o = tid, g4 = o >> 2, cm = o & 3;
        float c[VDIM];
#pragma unroll
        for (int i = 0; i < IN_F; ++i) {
            c[i]      = ((const float*)&Rs[i * GROUPS + g4])[cm];
            c[9 + i]  = ((const float*)&Bs[i * GROUPS + g4])[cm];  // S0 * B
            c[18 + i] = ((const float*)&Ws[i * GROUPS + g4])[cm];  // S1 * W
        }
        float sv = 0.f;
#pragma unroll
        for (int i = 0; i < VDIM; ++i) sv += M[NPAIR + i] * c[i];
        float q = 0.f;
        int t2 = 0;
        for (int i = 0; i < VDIM; ++i) {
            q += c[i] * c[i] * M[t2++];               // j == i
            for (int j = i + 1; j < VDIM; ++j)
                q += 2.f * c[i] * c[j] * M[t2++];
        }
        const float b = ((const float*)&bs4[g4])[cm];
        const float inv_n = 1.0f / (float)N_NODES;
        float mean  = (sv + (float)N_NODES * b) * inv_n;
        float sumsq = q + 2.f * b * sv + (float)N_NODES * b * b;
        float var   = sumsq * inv_n - mean * mean;
        float sc    = rsqrtf(var + BN_EPS) * gamma[o];
        scale[o] = sc;
        shift[o] = beta[o] - mean * sc;
    }
    __syncthreads();

    // matvec + normalized write: 252 threads x 4 nodes, g fixed per thread
    const int g = tid % GROUPS;
    if (tid < 252) {
        float4 sc4 = *(const float4*)&scale[g * 4];
        float4 sh4 = *(const float4*)&shift[g * 4];
#pragma unroll
        for (int k = 0; k < 4; ++k) {
            int p  = tid + k * 252;                  // 0..1007
            int nl = p / GROUPS;                     // 0..47
            int n  = nbase + nl;
            if (n < N_NODES) {
                float4 acc = bs4[g];
#pragma unroll
                for (int i = 0; i < IN_F; ++i) {
                    float xv = Xt[nl * IN_F + i];
                    float s0 = St[nl * 18 + i];
                    float s1 = St[nl * 18 + 9 + i];
                    float4 r = Rs[i * GROUPS + g];
                    float4 w = Ws[i * GROUPS + g];
                    float4 b = Bs[i * GROUPS + g];
                    acc.x += xv * r.x + s1 * w.x + s0 * b.x;
                    acc.y += xv * r.y + s1 * w.y + s0 * b.y;
                    acc.z += xv * r.z + s1 * w.z + s0 * b.z;
                    acc.w += xv * r.w + s1 * w.w + s0 * b.w;
                }
                acc.x = acc.x * sc4.x + sh4.x;
                acc.y = acc.y * sc4.y + sh4.y;
                acc.z = acc.z * sc4.z + sh4.z;
                acc.w = acc.w * sc4.w + sh4.w;
                *(float4*)&out[n * OUT_F + g * 4] = acc;
            }
        }
    }
}

extern "C" void kernel_launch(void* const* d_in, const int* in_sizes, int n_in,
                              void* d_out, int out_size, void* d_ws, size_t ws_size,
                              hipStream_t stream) {
    const float* x     = (const float*)d_in[0];
    const int*   ei    = (const int*)d_in[1];     // int64 in ref -> int32 here
    const float* ea    = (const float*)d_in[2];
    const float* nw    = (const float*)d_in[3];
    const float* nb    = (const float*)d_in[4];
    const float* root  = (const float*)d_in[5];
    const float* bias  = (const float*)d_in[6];
    const float* gamma = (const float*)d_in[7];
    const float* beta  = (const float*)d_in[8];
    float*       out   = (float*)d_out;

    float* wsf   = (float*)d_ws;
    int*   wsi   = (int*)d_ws;
    int*   cnt   = wsi + CNT_OFF;            // N ints
    float* statc = wsf + STATC_OFF;          // 32 x 408 floats
    float* slot  = wsf + SLOT_OFF;           // N*CAP*12 floats (76.8 MB)
    float* S     = wsf + S_OFF;              // N*18 floats (3.6 MB)

    hipMemsetAsync(cnt, 0, N_NODES * sizeof(int), stream);
    fill_slots_kernel<<<(E_EDGES + 255) / 256, 256, 0, stream>>>(x, ei, ea, cnt, slot, statc);
    gather_gram_kernel<<<NTILES, 256, 0, stream>>>(x, cnt, slot, S, statc);
    final_kernel<<<NTILES, 256, 0, stream>>>(x, S, nw, nb, root, bias,
                                             gamma, beta, statc, out);
}

// Round 13
// 121.177 us; speedup vs baseline: 1.0221x; 1.0221x over previous
//
#include <hip/hip_runtime.h>

#define N_NODES 50000
#define E_EDGES 250000
#define IN_F 9
#define OUT_F 84
#define GROUPS 21            // OUT_F / 4
#define BN_EPS 1e-5f

#define NB_TILE 48           // nodes per block-tile
#define NTILES ((N_NODES + NB_TILE - 1) / NB_TILE)   // 1042
#define NCOPIES 32           // sharded Gram accumulators
#define CAP 32               // slots per destination (P[deg>32] ~ 1e-11, Poisson(5))

#define VDIM 27              // v = (x[9], S0[9], S1[9])
#define NPAIR 378            // VDIM*(VDIM+1)/2 upper-triangle entries of M
#define NM 405               // NPAIR + VDIM (Sigma v)
#define SLEN 408             // padded stride per stat copy

// ws layout (4-byte units) — cnt and statc contiguous: ONE memset zeroes both
//   [0, 50000)        : cnt[N] per-dst degree counters (int)
//   [50048, 63104)    : statc — 32 copies x 408 (M[378], Sv[27]) (float)
//   [63232, 3263232)  : slot[N*CAP] int2 (src, ea_bits), rows 256B
//   [3263232, +N*18)  : S[N*18] per node S0[9], S1[9] (float)
#define CNT_OFF   0
#define STATC_OFF 50048
#define ZERO_WORDS 63104     // memset covers [0, 63104) words
#define SLOT_OFF  63232      // *4 B = 252928, %16 == 0
#define S_OFF     3263232

// ---------------------------------------------------------------------------
// K1: bucket edges by destination — one atomicAdd + one 8B store per edge.
// ---------------------------------------------------------------------------
__global__ void fill_slots_kernel(const int* __restrict__ ei,
                                  const float* __restrict__ ea,
                                  int* __restrict__ cnt,
                                  int2* __restrict__ slot) {
    int e = blockIdx.x * blockDim.x + threadIdx.x;
    if (e < E_EDGES) {
        int dst = ei[E_EDGES + e];
        int pos = atomicAdd(&cnt[dst], 1);
        if (pos < CAP)
            slot[dst * CAP + pos] = make_int2(ei[e], __float_as_int(ea[e]));
    }
}

// ---------------------------------------------------------------------------
// K2: gather + Gram, 48-node tiles (R11-proven).
//  phase 1: 192 threads stage slot records into LDS (line-granular int4)
//  phase 2: 432 (n,i) items gather with 4-wide-unrolled independent x loads
//  phase 3: Gram M_ij = sum_n V_i V_j (378) + Sv (27), sharded atomic fold
// ---------------------------------------------------------------------------
__global__ void gather_gram_kernel(const float* __restrict__ x,
                                   const int*   __restrict__ cnt,
                                   const int2*  __restrict__ slot,
                                   float* __restrict__ S,
                                   float* __restrict__ statc) {
    __shared__ float V[VDIM * (NB_TILE + 1)];        // [27][49]
    __shared__ __align__(16) int2 rec[NB_TILE][CAP]; // 12 KB
    __shared__ int cnt_s[NB_TILE];
    __shared__ unsigned char pI[NPAIR], pJ[NPAIR];

    const int tid = threadIdx.x;
    const int nbase = blockIdx.x * NB_TILE;

    // pair table (upper triangle, row-major): t -> (i, j)
    for (int t = tid; t < NPAIR; t += blockDim.x) {
        int tt = t, i = 0;
        while (tt >= VDIM - i) { tt -= VDIM - i; ++i; }
        pI[t] = (unsigned char)i;
        pJ[t] = (unsigned char)(i + tt);
    }
    if (tid < NB_TILE) {
        int n = nbase + tid;
        int c = (n < N_NODES) ? cnt[n] : 0;
        cnt_s[tid] = (c > CAP) ? CAP : c;
    }
    __syncthreads();

    // phase 1: copy records. thread = (node, quarter-line): 4 int4 = 8 slots
    if (tid < NB_TILE * 4) {
        int nl = tid >> 2, part = tid & 3;
        int c = cnt_s[nl];
        const int4* grow = (const int4*)&slot[(nbase + nl) * CAP];
        int4* lrow = (int4*)&rec[nl][0];
#pragma unroll
        for (int j = 0; j < 4; ++j) {
            int s = part * 8 + j * 2;               // first slot of this int4
            if (s < c) lrow[part * 4 + j] = grow[part * 4 + j];
        }
    }
    __syncthreads();

    // phase 2: gather — 432 items over 256 threads
    for (int it = tid; it < NB_TILE * IN_F; it += blockDim.x) {
        int nl = it / IN_F, i = it - nl * IN_F;
        int n = nbase + nl;
        float xv = 0.f, s0 = 0.f, s1 = 0.f;
        if (n < N_NODES) {
            xv = x[n * IN_F + i];
            int c = cnt_s[nl];
            const int2* r = rec[nl];
            int k = 0;
            for (; k + 4 <= c; k += 4) {           // 4 independent x loads
                int2 r0 = r[k], r1 = r[k+1], r2 = r[k+2], r3 = r[k+3];
                float a0 = x[r0.x * IN_F + i];
                float a1 = x[r1.x * IN_F + i];
                float a2 = x[r2.x * IN_F + i];
                float a3 = x[r3.x * IN_F + i];
                s0 += (a0 + a1) + (a2 + a3);
                s1 += __int_as_float(r0.y) * a0 + __int_as_float(r1.y) * a1
                    + __int_as_float(r2.y) * a2 + __int_as_float(r3.y) * a3;
            }
            for (; k < c; ++k) {
                int2 r0 = r[k];
                float a0 = x[r0.x * IN_F + i];
                s0 += a0;
                s1 += __int_as_float(r0.y) * a0;
            }
            S[n * 18 + i]     = s0;
            S[n * 18 + 9 + i] = s1;
        }
        V[i * (NB_TILE + 1) + nl]        = xv;
        V[(9 + i) * (NB_TILE + 1) + nl]  = s0;
        V[(18 + i) * (NB_TILE + 1) + nl] = s1;
    }
    __syncthreads();

    // phase 3: Gram entries, sharded fold
    float* sc = statc + (blockIdx.x & (NCOPIES - 1)) * SLEN;
    for (int t = tid; t < NM; t += blockDim.x) {
        float acc = 0.f;
        if (t < NPAIR) {
            const float* vi = &V[pI[t] * (NB_TILE + 1)];
            const float* vj = &V[pJ[t] * (NB_TILE + 1)];
#pragma unroll
            for (int n = 0; n < NB_TILE; ++n) acc += vi[n] * vj[n];
        } else {
            const float* vi = &V[(t - NPAIR) * (NB_TILE + 1)];
#pragma unroll
            for (int n = 0; n < NB_TILE; ++n) acc += vi[n];
        }
        atomicAdd(&sc[t], acc);
    }
}

// ---------------------------------------------------------------------------
// K3: final — reduce Gram copies, derive BN scale/shift analytically (all
// from LDS), matvec + normalized write in one pass. 1008 = 252*4 items.
//   sumsq_o = c^T M c + 2 b (Sv.c) + N b^2,  sum_o = Sv.c + N b
// ---------------------------------------------------------------------------
__global__ void final_kernel(const float* __restrict__ x,
                             const float* __restrict__ S,
                             const float* __restrict__ nw,
                             const float* __restrict__ nb,
                             const float* __restrict__ root,
                             const float* __restrict__ bias,
                             const float* __restrict__ gamma,
                             const float* __restrict__ beta,
                             const float* __restrict__ statc,
                             float* __restrict__ out) {
    __shared__ __align__(16) float4 Ws[IN_F * GROUPS];
    __shared__ __align__(16) float4 Bs[IN_F * GROUPS];
    __shared__ __align__(16) float4 Rs[IN_F * GROUPS];
    __shared__ __align__(16) float4 bs4[GROUPS];
    __shared__ float M[NM];
    __shared__ __align__(16) float scale[OUT_F];
    __shared__ __align__(16) float shift[OUT_F];
    __shared__ float Xt[NB_TILE * IN_F];
    __shared__ float St[NB_TILE * 18];

    const int tid = threadIdx.x;
    const int nbase = blockIdx.x * NB_TILE;

    // stage weights
    for (int t = tid; t < IN_F * GROUPS; t += blockDim.x) {
        Ws[t] = ((const float4*)nw)[t];
        Bs[t] = ((const float4*)nb)[t];
        Rs[t] = ((const float4*)root)[t];
    }
    if (tid < GROUPS) bs4[tid] = ((const float4*)bias)[tid];

    // stage tile x and S (432 items)
    for (int it = tid; it < NB_TILE * IN_F; it += blockDim.x) {
        int nl = it / IN_F, i = it - nl * IN_F;
        int n = nbase + nl;
        float xv = 0.f, s0 = 0.f, s1 = 0.f;
        if (n < N_NODES) {
            xv = x[n * IN_F + i];
            s0 = S[n * 18 + i];
            s1 = S[n * 18 + 9 + i];
        }
        Xt[nl * IN_F + i]   = xv;
        St[nl * 18 + i]     = s0;
        St[nl * 18 + 9 + i] = s1;
    }

    // reduce the 32 Gram copies
    for (int t = tid; t < NM; t += blockDim.x) {
        float a = 0.f;
#pragma unroll
        for (int c = 0; c < NCOPIES; ++c) a += statc[c * SLEN + t];
        M[t] = a;
    }
    __syncthreads();

    // scale/shift per channel — operands in LDS
    if (tid < OUT_F) {
        const int o = tid, g4 = o >> 2, cm = o & 3;
        float c[VDIM];
#pragma unroll
        for (int i = 0; i < IN_F; ++i) {
            c[i]      = ((const float*)&Rs[i * GROUPS + g4])[cm];
            c[9 + i]  = ((const float*)&Bs[i * GROUPS + g4])[cm];  // S0 * B
            c[18 + i] = ((const float*)&Ws[i * GROUPS + g4])[cm];  // S1 * W
        }
        float sv = 0.f;
#pragma unroll
        for (int i = 0; i < VDIM; ++i) sv += M[NPAIR + i] * c[i];
        float q = 0.f;
        int t2 = 0;
        for (int i = 0; i < VDIM; ++i) {
            q += c[i] * c[i] * M[t2++];               // j == i
            for (int j = i + 1; j < VDIM; ++j)
                q += 2.f * c[i] * c[j] * M[t2++];
        }
        const float b = ((const float*)&bs4[g4])[cm];
        const float inv_n = 1.0f / (float)N_NODES;
        float mean  = (sv + (float)N_NODES * b) * inv_n;
        float sumsq = q + 2.f * b * sv + (float)N_NODES * b * b;
        float var   = sumsq * inv_n - mean * mean;
        float sc    = rsqrtf(var + BN_EPS) * gamma[o];
        scale[o] = sc;
        shift[o] = beta[o] - mean * sc;
    }
    __syncthreads();

    // matvec + normalized write: 252 threads x 4 nodes, g fixed per thread
    const int g = tid % GROUPS;
    if (tid < 252) {
        float4 sc4 = *(const float4*)&scale[g * 4];
        float4 sh4 = *(const float4*)&shift[g * 4];
#pragma unroll
        for (int k = 0; k < 4; ++k) {
            int p  = tid + k * 252;                  // 0..1007
            int nl = p / GROUPS;                     // 0..47
            int n  = nbase + nl;
            if (n < N_NODES) {
                float4 acc = bs4[g];
#pragma unroll
                for (int i = 0; i < IN_F; ++i) {
                    float xv = Xt[nl * IN_F + i];
                    float s0 = St[nl * 18 + i];
                    float s1 = St[nl * 18 + 9 + i];
                    float4 r = Rs[i * GROUPS + g];
                    float4 w = Ws[i * GROUPS + g];
                    float4 b = Bs[i * GROUPS + g];
                    acc.x += xv * r.x + s1 * w.x + s0 * b.x;
                    acc.y += xv * r.y + s1 * w.y + s0 * b.y;
                    acc.z += xv * r.z + s1 * w.z + s0 * b.z;
                    acc.w += xv * r.w + s1 * w.w + s0 * b.w;
                }
                acc.x = acc.x * sc4.x + sh4.x;
                acc.y = acc.y * sc4.y + sh4.y;
                acc.z = acc.z * sc4.z + sh4.z;
                acc.w = acc.w * sc4.w + sh4.w;
                *(float4*)&out[n * OUT_F + g * 4] = acc;
            }
        }
    }
}

extern "C" void kernel_launch(void* const* d_in, const int* in_sizes, int n_in,
                              void* d_out, int out_size, void* d_ws, size_t ws_size,
                              hipStream_t stream) {
    const float* x     = (const float*)d_in[0];
    const int*   ei    = (const int*)d_in[1];     // int64 in ref -> int32 here
    const float* ea    = (const float*)d_in[2];
    const float* nw    = (const float*)d_in[3];
    const float* nb    = (const float*)d_in[4];
    const float* root  = (const float*)d_in[5];
    const float* bias  = (const float*)d_in[6];
    const float* gamma = (const float*)d_in[7];
    const float* beta  = (const float*)d_in[8];
    float*       out   = (float*)d_out;

    float* wsf   = (float*)d_ws;
    int*   wsi   = (int*)d_ws;
    int*   cnt   = wsi + CNT_OFF;            // N ints
    float* statc = wsf + STATC_OFF;          // 32 x 408 floats
    int2*  slot  = (int2*)(wsi + SLOT_OFF);  // N*CAP int2 (12.8 MB)
    float* S     = wsf + S_OFF;              // N*18 floats (3.6 MB)

    // one memset zeroes cnt AND statc (contiguous; 0.0f == all-zero bits)
    hipMemsetAsync(wsi, 0, ZERO_WORDS * sizeof(int), stream);
    fill_slots_kernel<<<(E_EDGES + 255) / 256, 256, 0, stream>>>(ei, ea, cnt, slot);
    gather_gram_kernel<<<NTILES, 256, 0, stream>>>(x, cnt, slot, S, statc);
    final_kernel<<<NTILES, 256, 0, stream>>>(x, S, nw, nb, root, bias,
                                             gamma, beta, statc, out);
}